// Round 8
// baseline (247.453 us; speedup 1.0000x reference)
//
#include <hip/hip_runtime.h>
#include <stdint.h>

typedef __bf16 bf16;
typedef __attribute__((ext_vector_type(2))) __bf16 bf16x2;
typedef __attribute__((ext_vector_type(4))) __bf16 bf16x4;
typedef __attribute__((ext_vector_type(8))) __bf16 bf16x8;
typedef __attribute__((ext_vector_type(4))) float f32x4;
typedef __attribute__((ext_vector_type(4))) short s16x4;

#define B_  2
#define S_  2048
#define H_  1024
#define NH_ 16
#define HD_ 64

// async 16B global->LDS. LDS dest = wave-uniform base + lane*16.
__device__ __forceinline__ void glds16(const bf16* g, bf16* l) {
  __builtin_amdgcn_global_load_lds(
      (const __attribute__((address_space(1))) uint32_t*)g,
      (__attribute__((address_space(3))) uint32_t*)l, 16, 0, 0);
}

// PV MFMA: 16x16x16 bf16 — B operand layout (k=quad*4+e, col=l15) matches the
// S^T MFMA D layout exactly, so softmax P registers feed it with NO relayout.
__device__ __forceinline__ f32x4 pv_mfma(bf16x4 a, bf16x4 b, f32x4 c) {
#if __has_builtin(__builtin_amdgcn_mfma_f32_16x16x16bf16_1k)
  union U { bf16x4 h; s16x4 s; };
  U ua; ua.h = a;
  U ub; ub.h = b;
  return __builtin_amdgcn_mfma_f32_16x16x16bf16_1k(ua.s, ub.s, c, 0, 0, 0);
#else
  f32x4 d;
  asm volatile("v_mfma_f32_16x16x16_bf16 %0, %1, %2, %3\n\ts_nop 7\n\ts_nop 7"
               : "=v"(d) : "v"(a), "v"(b), "v"(c));
  return d;
#endif
}

// 16 f32 (4 float4) -> 16 bf16 (2 bf16x8) LDS store. RNE, same numerics as
// the old standalone cvt kernel.
__device__ __forceinline__ void cvt16_store(const float4 v[4], bf16* dst) {
  bf16x8 o0, o1;
  o0[0] = (bf16)v[0].x; o0[1] = (bf16)v[0].y; o0[2] = (bf16)v[0].z; o0[3] = (bf16)v[0].w;
  o0[4] = (bf16)v[1].x; o0[5] = (bf16)v[1].y; o0[6] = (bf16)v[1].z; o0[7] = (bf16)v[1].w;
  o1[0] = (bf16)v[2].x; o1[1] = (bf16)v[2].y; o1[2] = (bf16)v[2].z; o1[3] = (bf16)v[2].w;
  o1[4] = (bf16)v[3].x; o1[5] = (bf16)v[3].y; o1[6] = (bf16)v[3].z; o1[7] = (bf16)v[3].w;
  *(bf16x8*)(dst)     = o0;
  *(bf16x8*)(dst + 8) = o1;
}

#define LD4(dst, src)                                                       \
  { dst[0] = *(const float4*)(src);      dst[1] = *(const float4*)((src) + 4); \
    dst[2] = *(const float4*)((src) + 8); dst[3] = *(const float4*)((src) + 12); }

// ---------------------------------------------------------------------------
// Fused QKV GEMM reading fp32 X and fp32 weights DIRECTLY (no cvt kernel,
// no bf16 roundtrip).  m97-style 128x128xBK32, double-buffered LDS, one
// barrier per K-iter.  Staging = global f32 -> regs -> v_cvt -> ds_write
// bf16 (T14 issue-early/write-late); LDS layout and MFMA inner loop are
// byte-identical to the proven gemm_bt_bias.  N fused over [Wq;Wk;Wv]:
// grid (3072/128) x (4096/128) = 24 x 32 = 768 blocks (3/CU).  A 128-row
// B-tile never straddles a 1024-col segment, so seg is per-block uniform.
// Softmax scale qscl folded into the Q segment's epilogue.
// ---------------------------------------------------------------------------
__global__ __launch_bounds__(256) void gemm_qkv_f32(
    const float* __restrict__ X,
    const float* __restrict__ Wqf, const float* __restrict__ Wkf,
    const float* __restrict__ Wvf,
    const float* __restrict__ bq, const float* __restrict__ bk,
    const float* __restrict__ bv,
    bf16* __restrict__ Yq, bf16* __restrict__ Yk, bf16* __restrict__ Yv,
    float qscl)
{
  __shared__ __align__(16) bf16 As[2][128 * 32];
  __shared__ __align__(16) bf16 Bs[2][128 * 32];

  const int tid  = threadIdx.x;
  const int lane = tid & 63;
  const int wave = tid >> 6;

  const int m0  = blockIdx.y * 128;
  const int n0g = blockIdx.x * 128;           // 0..2944
  const int seg = n0g >> 10;                  // 0=Q 1=K 2=V
  const float* W    = seg == 0 ? Wqf : (seg == 1 ? Wkf : Wvf);
  const float* bias = seg == 0 ? bq  : (seg == 1 ? bk  : bv);
  bf16*        Y    = seg == 0 ? Yq  : (seg == 1 ? Yk  : Yv);
  const float  ysc  = seg == 0 ? qscl : 1.0f;
  const int    n0   = n0g & 1023;

  const int wm = (wave >> 1) * 64;
  const int wn = (wave & 1) * 64;

  // staging map: thread -> (row sr, 16-col half sc) of the 128x32 f32 tile
  const int sr = tid >> 1, sc = (tid & 1) * 16;
  const float* Xs = X + (size_t)(m0 + sr) * 1024 + sc;
  const float* Ws = W + (size_t)(n0 + sr) * 1024 + sc;
  const int sdst = sr * 32 + sc;

  f32x4 acc[4][4] = {};
  float4 va[4], vb[4];

  // prologue: tile 0 -> buf 0
  LD4(va, Xs); LD4(vb, Ws);
  cvt16_store(va, &As[0][sdst]);
  cvt16_store(vb, &Bs[0][sdst]);

  int pb = 0;
  for (int k0 = 0; k0 < 1024; k0 += 32, pb ^= 1) {
    __syncthreads();                 // buf pb published (ds_writes drained)
    const bool pre = k0 + 32 < 1024;
    if (pre) { LD4(va, Xs + k0 + 32); LD4(vb, Ws + k0 + 32); }   // issue early

    bf16x8 a[4], b[4];
#pragma unroll
    for (int i = 0; i < 4; ++i)
      a[i] = *(const bf16x8*)&As[pb][(wm + i * 16 + (lane & 15)) * 32 + (lane >> 4) * 8];
#pragma unroll
    for (int i = 0; i < 4; ++i)
      b[i] = *(const bf16x8*)&Bs[pb][(wn + i * 16 + (lane & 15)) * 32 + (lane >> 4) * 8];
#pragma unroll
    for (int mi = 0; mi < 4; ++mi)
#pragma unroll
      for (int ni = 0; ni < 4; ++ni)
        acc[mi][ni] = __builtin_amdgcn_mfma_f32_16x16x32_bf16(a[mi], b[ni], acc[mi][ni], 0, 0, 0);

    if (pre) {                        // write late, after the MFMA cover
      cvt16_store(va, &As[pb ^ 1][sdst]);
      cvt16_store(vb, &Bs[pb ^ 1][sdst]);
    }
  }

#pragma unroll
  for (int mi = 0; mi < 4; ++mi) {
    const int row = m0 + wm + mi * 16 + (lane >> 4) * 4;
#pragma unroll
    for (int ni = 0; ni < 4; ++ni) {
      const int col = n0 + wn + ni * 16 + (lane & 15);
      const float bvv = bias[col];
#pragma unroll
      for (int r = 0; r < 4; ++r)
        Y[(size_t)(row + r) * 1024 + col] = (bf16)((acc[mi][ni][r] + bvv) * ysc);
    }
  }
}

// ---------------------------------------------------------------------------
// O-projection: A = attn output (bf16, glds16 staging exactly as the proven
// gemm_bt_bias), B = Wo read DIRECTLY as fp32 (reg-staged + cvt).  fp32 out.
// 128x128xBK32, 8x32 = 256 blocks.
// ---------------------------------------------------------------------------
__global__ __launch_bounds__(256) void gemm_o_f32w(
    const bf16* __restrict__ X, const float* __restrict__ W,
    const float* __restrict__ bias, float* __restrict__ Y)
{
  __shared__ __align__(16) bf16 As[2][128 * 32];
  __shared__ __align__(16) bf16 Bs[2][128 * 32];

  const int tid  = threadIdx.x;
  const int lane = tid & 63;
  const int wave = tid >> 6;
  const int m0 = blockIdx.y * 128;
  const int n0 = blockIdx.x * 128;
  const int wm = (wave >> 1) * 64;
  const int wn = (wave & 1) * 64;

  // A staging: glds16 chunk map (unchanged from gemm_bt_bias)
  const int r0 = tid >> 2,            c0 = (tid & 3) * 8;
  const int r1 = (256 + tid) >> 2,    c1 = ((256 + tid) & 3) * 8;
  const int cb0 = (wave * 64) * 8;
  const int cb1 = (256 + wave * 64) * 8;

  // B staging: f32 reg-stage map
  const int sr = tid >> 1, sc = (tid & 1) * 16;
  const float* Ws = W + (size_t)(n0 + sr) * 1024 + sc;
  const int sdst = sr * 32 + sc;

  f32x4 acc[4][4] = {};
  float4 vb[4];

  // prologue
  glds16(X + (size_t)(m0 + r0) * 1024 + c0, &As[0][cb0]);
  glds16(X + (size_t)(m0 + r1) * 1024 + c1, &As[0][cb1]);
  LD4(vb, Ws);
  cvt16_store(vb, &Bs[0][sdst]);

  int pb = 0;
  for (int k0 = 0; k0 < 1024; k0 += 32, pb ^= 1) {
    __syncthreads();
    const bool pre = k0 + 32 < 1024;
    if (pre) {
      const int kn = k0 + 32;
      glds16(X + (size_t)(m0 + r0) * 1024 + kn + c0, &As[pb ^ 1][cb0]);
      glds16(X + (size_t)(m0 + r1) * 1024 + kn + c1, &As[pb ^ 1][cb1]);
      LD4(vb, Ws + kn);
    }

    bf16x8 a[4], b[4];
#pragma unroll
    for (int i = 0; i < 4; ++i)
      a[i] = *(const bf16x8*)&As[pb][(wm + i * 16 + (lane & 15)) * 32 + (lane >> 4) * 8];
#pragma unroll
    for (int i = 0; i < 4; ++i)
      b[i] = *(const bf16x8*)&Bs[pb][(wn + i * 16 + (lane & 15)) * 32 + (lane >> 4) * 8];
#pragma unroll
    for (int mi = 0; mi < 4; ++mi)
#pragma unroll
      for (int ni = 0; ni < 4; ++ni)
        acc[mi][ni] = __builtin_amdgcn_mfma_f32_16x16x32_bf16(a[mi], b[ni], acc[mi][ni], 0, 0, 0);

    if (pre) cvt16_store(vb, &Bs[pb ^ 1][sdst]);
  }

#pragma unroll
  for (int mi = 0; mi < 4; ++mi) {
    const int row = m0 + wm + mi * 16 + (lane >> 4) * 4;
#pragma unroll
    for (int ni = 0; ni < 4; ++ni) {
      const int col = n0 + wn + ni * 16 + (lane & 15);
      const float bvv = bias[col];
#pragma unroll
      for (int r = 0; r < 4; ++r)
        Y[(size_t)(row + r) * 1024 + col] = acc[mi][ni][r] + bvv;
    }
  }
}

// ---------------------------------------------------------------------------
// Flash attention, causal (R3/R7 version verbatim — measured 57.6 us).
// Paired q-tiles (p, 31-p) share one merged k-loop; double-buffered K/V, one
// barrier per iter; P in registers (16x16x16 PV); defer-max with algebraic
// post-PV fixup; Q pre-scaled by the QKV GEMM.
// ---------------------------------------------------------------------------
__device__ __forceinline__ void attn_tile_step(
    const bf16* Ksb, const bf16* Vtb, const bf16x8 bq[2], int qrow, int k0,
    bool maskit, float& mr, float& lr, f32x4 oacc[4], int l15, int quad)
{
  // ---- S^T = K Q^T ----
  f32x4 sacc[8] = {};
  __builtin_amdgcn_s_setprio(1);
#pragma unroll
  for (int ks = 0; ks < 2; ++ks) {
#pragma unroll
    for (int mb = 0; mb < 8; ++mb) {
      const int row = mb * 16 + l15;
      const int ch  = (ks * 4 + quad) ^ (l15 & 7);   // XOR de-swizzle
      bf16x8 ak = *(const bf16x8*)&Ksb[row * 64 + ch * 8];
      sacc[mb] = __builtin_amdgcn_mfma_f32_16x16x32_bf16(ak, bq[ks], sacc[mb], 0, 0, 0);
    }
  }
  __builtin_amdgcn_s_setprio(0);

  // causal mask (only on the final k-tile of this q-tile)
  if (maskit) {
#pragma unroll
    for (int mb = 0; mb < 8; ++mb) {
      const int kb = k0 + mb * 16 + quad * 4;
#pragma unroll
      for (int r = 0; r < 4; ++r)
        if (kb + r > qrow) sacc[mb][r] = -1e30f;
    }
  }

  // max tree + shuffles — runs in PARALLEL with the exp2/PV chain below
  float mx = -1e30f;
#pragma unroll
  for (int mb = 0; mb < 8; ++mb)
    mx = fmaxf(mx, fmaxf(fmaxf(sacc[mb][0], sacc[mb][1]),
                         fmaxf(sacc[mb][2], sacc[mb][3])));
  mx = fmaxf(mx, __shfl_xor(mx, 16, 64));
  mx = fmaxf(mx, __shfl_xor(mx, 32, 64));

  // speculative exp2 with CURRENT mr (no dependence on mx)
  float sum = 0.0f;
  bf16x4 pwv[8];
#pragma unroll
  for (int mb = 0; mb < 8; ++mb) {
    bf16x4 pw;
#pragma unroll
    for (int r = 0; r < 4; ++r) {
      const float p = __builtin_amdgcn_exp2f(sacc[mb][r] - mr);
      sum += p;
      pw[r] = (bf16)p;
    }
    pwv[mb] = pw;
  }
  sum += __shfl_xor(sum, 16, 64);
  sum += __shfl_xor(sum, 32, 64);

  // ---- O^T += V^T P^T : 16x16x16, P direct from registers ----
  __builtin_amdgcn_s_setprio(1);
#pragma unroll
  for (int mb = 0; mb < 8; ++mb) {
#pragma unroll
    for (int db = 0; db < 4; ++db) {
      const int vch = ((mb * 4 + quad) ^ (l15 & 7)) * 4;
      bf16x4 av = *(const bf16x4*)&Vtb[(db * 16 + l15) * 128 + vch];
      oacc[db] = pv_mfma(av, pwv[mb], oacc[db]);
    }
  }
  __builtin_amdgcn_s_setprio(0);

  lr += sum;
  // rare fixup: rescale AFTER accumulation (exact: O' = a*(O_old + P·V))
  if (!__all(mx <= mr + 8.0f)) {
    const float mnew  = fmaxf(mr, mx);
    const float alpha = __builtin_amdgcn_exp2f(mr - mnew);
    lr *= alpha;
#pragma unroll
    for (int db = 0; db < 4; ++db)
#pragma unroll
      for (int r = 0; r < 4; ++r) oacc[db][r] *= alpha;
    mr = mnew;
  }
}

__global__ __launch_bounds__(256, 2) void attn_causal(
    const bf16* __restrict__ Q, const bf16* __restrict__ K,
    const bf16* __restrict__ V, bf16* __restrict__ O)
{
  // XCD-chunked decode: all 16 pair-blocks of a bh land on one XCD (lin%8).
  const int lin  = blockIdx.x;               // 0..511
  const int slot = lin >> 3;                 // 0..63
  const int bh   = (lin & 7) * 4 + (slot >> 4);
  const int pair = slot & 15;
  const int b    = bh >> 4;
  const int h    = bh & 15;

  const int tid  = threadIdx.x;
  const int lane = tid & 63;
  const int wave = tid >> 6;
  const int quad = lane >> 4;
  const int l15  = lane & 15;
  const size_t headoff = (size_t)b * S_ * H_ + (size_t)h * HD_;
  const bf16* Kp = K + headoff;
  const bf16* Vp = V + headoff;

  __shared__ __align__(16) bf16 Ks[2][128 * 64];    // unpadded, XOR-swizzled
  __shared__ __align__(16) bf16 Vt[2][64 * 128];    // Vt[d][key], XOR-swizzled

  const int qlo = pair, qhi = 31 - pair;
  const int nl  = (qlo >> 1) + 1;      // 1..8
  const int nh  = (qhi >> 1) + 1;      // 9..16  (nl < nh always)
  const int qrowL = qlo * 64 + wave * 16 + l15;
  const int qrowH = qhi * 64 + wave * 16 + l15;

  // Q fragments in registers for the whole block (pre-scaled by QKV GEMM)
  bf16x8 bqL[2], bqH[2];
  bqL[0] = *(const bf16x8*)(Q + headoff + (size_t)qrowL * H_ + quad * 8);
  bqL[1] = *(const bf16x8*)(Q + headoff + (size_t)qrowL * H_ + 32 + quad * 8);
  bqH[0] = *(const bf16x8*)(Q + headoff + (size_t)qrowH * H_ + quad * 8);
  bqH[1] = *(const bf16x8*)(Q + headoff + (size_t)qrowH * H_ + 32 + quad * 8);

  const int vr = lane * 2;          // V: two adjacent key rows per thread
  const int vc = wave * 16;         //    16 of 64 head dims per wave

#define STAGE_K(k0_, buf_)                                                  \
  {                                                                         \
    _Pragma("unroll")                                                       \
    for (int i = 0; i < 4; ++i) {                                           \
      const int n = i * 256 + tid;                                          \
      const int row = n >> 3;                                               \
      const int cg  = (n & 7) ^ (row & 7);                                  \
      glds16(Kp + (size_t)((k0_) + row) * H_ + cg * 8,                      \
             &Ks[buf_][(i * 256 + wave * 64) * 8]);                         \
    }                                                                       \
  }

#define LOAD_V(k0_)                                                         \
  {                                                                         \
    vreg[0] = *(const bf16x8*)(Vp + (size_t)((k0_) + vr) * H_ + vc);        \
    vreg[1] = *(const bf16x8*)(Vp + (size_t)((k0_) + vr) * H_ + vc + 8);    \
    vreg[2] = *(const bf16x8*)(Vp + (size_t)((k0_) + vr + 1) * H_ + vc);    \
    vreg[3] = *(const bf16x8*)(Vp + (size_t)((k0_) + vr + 1) * H_ + vc + 8);\
  }

// Vt write with chunk-XOR swizzle: chunk (4 elems) index = (vr>>2) ^ (row&7).
#define WRITE_V(buf_)                                                       \
  {                                                                         \
    _Pragma("unroll")                                                       \
    for (int e = 0; e < 8; ++e) {                                           \
      const int sw = (((vr >> 2) ^ e) * 4) + (vr & 3);                      \
      bf16x2 p0; p0[0] = vreg[0][e]; p0[1] = vreg[2][e];                    \
      *(bf16x2*)&Vt[buf_][(vc + e) * 128 + sw] = p0;                        \
      bf16x2 p1; p1[0] = vreg[1][e]; p1[1] = vreg[3][e];                    \
      *(bf16x2*)&Vt[buf_][(vc + 8 + e) * 128 + sw] = p1;                    \
    }                                                                       \
  }

  bf16x8 vreg[4];

  // prologue: tile 0 -> buf 0
  STAGE_K(0, 0);
  LOAD_V(0);
  WRITE_V(0);
  __syncthreads();

  float mrL = 0.0f, lrL = 0.0f, mrH = 0.0f, lrH = 0.0f;
  f32x4 oL[4] = {}, oH[4] = {};

  for (int it = 0; it < nh; ++it) {
    const int c = it & 1;
    const bool pre = (it + 1 < nh);

    if (pre) {                       // prefetch tile it+1 into buf c^1
      STAGE_K((it + 1) * 128, c ^ 1);
      LOAD_V((it + 1) * 128);
    }

    attn_tile_step(Ks[c], Vt[c], bqH, qrowH, it * 128, it == nh - 1,
                   mrH, lrH, oH, l15, quad);
    if (it < nl)
      attn_tile_step(Ks[c], Vt[c], bqL, qrowL, it * 128, it == nl - 1,
                     mrL, lrL, oL, l15, quad);

    if (pre) {
      WRITE_V(c ^ 1);                // reg->LDS after compute (write-late)
      __syncthreads();               // drains glds + V writes; publishes c^1
    }
  }

  // epilogues
  const float invL = 1.0f / lrL;
#pragma unroll
  for (int db = 0; db < 4; ++db) {
    bf16x4 o;
#pragma unroll
    for (int r = 0; r < 4; ++r) o[r] = (bf16)(oL[db][r] * invL);
    *(bf16x4*)(O + headoff + (size_t)qrowL * H_ + db * 16 + quad * 4) = o;
  }
  const float invH = 1.0f / lrH;
#pragma unroll
  for (int db = 0; db < 4; ++db) {
    bf16x4 o;
#pragma unroll
    for (int r = 0; r < 4; ++r) o[r] = (bf16)(oH[db][r] * invH);
    *(bf16x4*)(O + headoff + (size_t)qrowH * H_ + db * 16 + quad * 4) = o;
  }
#undef STAGE_K
#undef LOAD_V
#undef WRITE_V
}

extern "C" void kernel_launch(void* const* d_in, const int* in_sizes, int n_in,
                              void* d_out, int out_size, void* d_ws, size_t ws_size,
                              hipStream_t stream) {
  const float* hs = (const float*)d_in[0];
  const float* Wq = (const float*)d_in[1]; const float* bq = (const float*)d_in[2];
  const float* Wk = (const float*)d_in[3]; const float* bk = (const float*)d_in[4];
  const float* Wv = (const float*)d_in[5]; const float* bv = (const float*)d_in[6];
  const float* Wo = (const float*)d_in[7]; const float* bo = (const float*)d_in[8];
  float* out = (float*)d_out;

  const size_t elems = (size_t)B_ * S_ * H_;   // 4,194,304
  // workspace (40 MB): Qw | Kw | Vw | AO, 8 MB each (bf16)
  bf16* Qw = (bf16*)d_ws;
  bf16* Kw = Qw + elems;
  bf16* Vw = Kw + elems;
  bf16* AO = Vw + elems;

  const float QSCL = 0.125f * 1.44269504f;   // (1/sqrt(64)) * log2(e)

  // 3 dispatches (was 4): conversion folded into the GEMM staging paths.
  gemm_qkv_f32<<<dim3(24, 32), dim3(256), 0, stream>>>(
      hs, Wq, Wk, Wv, bq, bk, bv, Qw, Kw, Vw, QSCL);

  attn_causal<<<dim3(512), dim3(256), 0, stream>>>(Qw, Kw, Vw, AO);

  gemm_o_f32w<<<dim3(8, 32), dim3(256), 0, stream>>>(AO, Wo, bo, out);
}

// Round 9
// 219.328 us; speedup vs baseline: 1.1282x; 1.1282x over previous
//
#include <hip/hip_runtime.h>
#include <stdint.h>

typedef __bf16 bf16;
typedef __attribute__((ext_vector_type(2))) __bf16 bf16x2;
typedef __attribute__((ext_vector_type(4))) __bf16 bf16x4;
typedef __attribute__((ext_vector_type(8))) __bf16 bf16x8;
typedef __attribute__((ext_vector_type(4))) float f32x4;
typedef __attribute__((ext_vector_type(4))) short s16x4;

#define B_  2
#define S_  2048
#define H_  1024
#define NH_ 16
#define HD_ 64

// async 16B global->LDS. LDS dest = wave-uniform base + lane*16.
__device__ __forceinline__ void glds16(const bf16* g, bf16* l) {
  __builtin_amdgcn_global_load_lds(
      (const __attribute__((address_space(1))) uint32_t*)g,
      (__attribute__((address_space(3))) uint32_t*)l, 16, 0, 0);
}

// PV MFMA: 16x16x16 bf16 — B operand layout (k=quad*4+e, col=l15) matches the
// S^T MFMA D layout exactly, so softmax P registers feed it with NO relayout.
__device__ __forceinline__ f32x4 pv_mfma(bf16x4 a, bf16x4 b, f32x4 c) {
#if __has_builtin(__builtin_amdgcn_mfma_f32_16x16x16bf16_1k)
  union U { bf16x4 h; s16x4 s; };
  U ua; ua.h = a;
  U ub; ub.h = b;
  return __builtin_amdgcn_mfma_f32_16x16x16bf16_1k(ua.s, ub.s, c, 0, 0, 0);
#else
  f32x4 d;
  asm volatile("v_mfma_f32_16x16x16_bf16 %0, %1, %2, %3\n\ts_nop 7\n\ts_nop 7"
               : "=v"(d) : "v"(a), "v"(b), "v"(c));
  return d;
#endif
}

// 8 f32 -> bf16x8 (RNE, same numerics as the old standalone cvt kernel)
__device__ __forceinline__ bf16x8 cvt8(const float4 a, const float4 b) {
  bf16x8 o;
  o[0] = (bf16)a.x; o[1] = (bf16)a.y; o[2] = (bf16)a.z; o[3] = (bf16)a.w;
  o[4] = (bf16)b.x; o[5] = (bf16)b.y; o[6] = (bf16)b.z; o[7] = (bf16)b.w;
  return o;
}

// ---------------------------------------------------------------------------
// Fused QKV GEMM reading fp32 X and fp32 weights DIRECTLY (no cvt kernel).
// m97-style 128x128xBK32, double-buffered LDS, one barrier per K-iter.
// R9 staging fix: LINEAR chunk map — chunk c = tid (and tid+256), row=c>>2,
// col8=(c&3)*8, LDS elem offset c*8.  Identical layout to glds16 staging:
// the wave's 64 ds_write_b128 land at consecutive 16B addresses ->
// CONFLICT-FREE (R8's map was a 16-way write conflict, 6.29M cycles).
// Global side: 4 consecutive lanes read one contiguous 128B row segment.
// XCD grouping: each XCD owns 4 consecutive by row-panels (X L2 locality;
// W cross-XCD re-reads are L3-served).
// ---------------------------------------------------------------------------
__global__ __launch_bounds__(256) void gemm_qkv_f32(
    const float* __restrict__ X,
    const float* __restrict__ Wqf, const float* __restrict__ Wkf,
    const float* __restrict__ Wvf,
    const float* __restrict__ bq, const float* __restrict__ bk,
    const float* __restrict__ bv,
    bf16* __restrict__ Yq, bf16* __restrict__ Yk, bf16* __restrict__ Yv,
    float qscl)
{
  __shared__ __align__(16) bf16 As[2][128 * 32];
  __shared__ __align__(16) bf16 Bs[2][128 * 32];

  const int tid  = threadIdx.x;
  const int lane = tid & 63;
  const int wave = tid >> 6;

  // XCD-grouped decode: 768 = 8 xcd * (4 by * 24 bx)
  const int f   = blockIdx.x;
  const int xcd = f & 7;
  const int i   = f >> 3;              // 0..95
  const int bx  = i % 24;
  const int by  = xcd * 4 + i / 24;
  const int m0  = by * 128;
  const int n0g = bx * 128;            // 0..2944
  const int seg = n0g >> 10;           // 0=Q 1=K 2=V
  const float* W    = seg == 0 ? Wqf : (seg == 1 ? Wkf : Wvf);
  const float* bias = seg == 0 ? bq  : (seg == 1 ? bk  : bv);
  bf16*        Y    = seg == 0 ? Yq  : (seg == 1 ? Yk  : Yv);
  const float  ysc  = seg == 0 ? qscl : 1.0f;
  const int    n0   = n0g & 1023;

  const int wm = (wave >> 1) * 64;
  const int wn = (wave & 1) * 64;

  // linear chunk map: chunks tid and tid+256; row=c>>2, col8=(c&3)*8
  const int r0 = tid >> 2, q0 = (tid & 3) * 8;    // chunk tid
  const int r1 = r0 + 64;                          // chunk tid+256 (same q0)
  const float* Xa0 = X + (size_t)(m0 + r0) * 1024 + q0;
  const float* Xa1 = X + (size_t)(m0 + r1) * 1024 + q0;
  const float* Wb0 = W + (size_t)(n0 + r0) * 1024 + q0;
  const float* Wb1 = W + (size_t)(n0 + r1) * 1024 + q0;

  f32x4 acc[4][4] = {};
  float4 va[4], vb[4];

#define LDT(k)                                                              \
  { va[0] = *(const float4*)(Xa0 + (k));  va[1] = *(const float4*)(Xa0 + (k) + 4); \
    va[2] = *(const float4*)(Xa1 + (k));  va[3] = *(const float4*)(Xa1 + (k) + 4); \
    vb[0] = *(const float4*)(Wb0 + (k));  vb[1] = *(const float4*)(Wb0 + (k) + 4); \
    vb[2] = *(const float4*)(Wb1 + (k));  vb[3] = *(const float4*)(Wb1 + (k) + 4); }
#define STT(buf)                                                            \
  { *(bf16x8*)&As[buf][tid * 8]         = cvt8(va[0], va[1]);               \
    *(bf16x8*)&As[buf][(tid + 256) * 8] = cvt8(va[2], va[3]);               \
    *(bf16x8*)&Bs[buf][tid * 8]         = cvt8(vb[0], vb[1]);               \
    *(bf16x8*)&Bs[buf][(tid + 256) * 8] = cvt8(vb[2], vb[3]); }

  // prologue: tile 0 -> buf 0
  LDT(0);
  STT(0);

  int pb = 0;
  for (int k0 = 0; k0 < 1024; k0 += 32, pb ^= 1) {
    __syncthreads();                 // buf pb published (ds_writes drained)
    const bool pre = k0 + 32 < 1024;
    if (pre) LDT(k0 + 32);           // issue early (covered by frags+MFMA)

    bf16x8 a[4], b[4];
#pragma unroll
    for (int j = 0; j < 4; ++j)
      a[j] = *(const bf16x8*)&As[pb][(wm + j * 16 + (lane & 15)) * 32 + (lane >> 4) * 8];
#pragma unroll
    for (int j = 0; j < 4; ++j)
      b[j] = *(const bf16x8*)&Bs[pb][(wn + j * 16 + (lane & 15)) * 32 + (lane >> 4) * 8];
#pragma unroll
    for (int mi = 0; mi < 4; ++mi)
#pragma unroll
      for (int ni = 0; ni < 4; ++ni)
        acc[mi][ni] = __builtin_amdgcn_mfma_f32_16x16x32_bf16(a[mi], b[ni], acc[mi][ni], 0, 0, 0);

    if (pre) STT(pb ^ 1);            // write late, after the MFMA cover
  }

#pragma unroll
  for (int mi = 0; mi < 4; ++mi) {
    const int row = m0 + wm + mi * 16 + (lane >> 4) * 4;
#pragma unroll
    for (int ni = 0; ni < 4; ++ni) {
      const int col = n0 + wn + ni * 16 + (lane & 15);
      const float bvv = bias[col];
#pragma unroll
      for (int r = 0; r < 4; ++r)
        Y[(size_t)(row + r) * 1024 + col] = (bf16)((acc[mi][ni][r] + bvv) * ysc);
    }
  }
#undef LDT
#undef STT
}

// ---------------------------------------------------------------------------
// O-projection: A = attn output (bf16, glds16 staging — proven path),
// B = Wo fp32 with the linear conflict-free reg-staging.  fp32 out + bias.
// 128x128xBK32, 256 blocks, XCD-grouped by row-panel.
// ---------------------------------------------------------------------------
__global__ __launch_bounds__(256) void gemm_o_f32w(
    const bf16* __restrict__ X, const float* __restrict__ W,
    const float* __restrict__ bias, float* __restrict__ Y)
{
  __shared__ __align__(16) bf16 As[2][128 * 32];
  __shared__ __align__(16) bf16 Bs[2][128 * 32];

  const int tid  = threadIdx.x;
  const int lane = tid & 63;
  const int wave = tid >> 6;

  // XCD-grouped decode: 256 = 8 xcd * (4 by * 8 bx)
  const int f   = blockIdx.x;
  const int xcd = f & 7;
  const int i   = f >> 3;              // 0..31
  const int bx  = i % 8;
  const int by  = xcd * 4 + i / 8;
  const int m0  = by * 128;
  const int n0  = bx * 128;

  const int wm = (wave >> 1) * 64;
  const int wn = (wave & 1) * 64;

  // A staging: glds16 chunk map (unchanged from proven gemm_bt_bias)
  const int ar0 = tid >> 2,           ac0 = (tid & 3) * 8;
  const int ar1 = (256 + tid) >> 2,   ac1 = ((256 + tid) & 3) * 8;
  const int cb0 = (wave * 64) * 8;
  const int cb1 = (256 + wave * 64) * 8;

  // B staging: linear chunk map, f32 source
  const int r0 = tid >> 2, q0 = (tid & 3) * 8;
  const int r1 = r0 + 64;
  const float* Wb0 = W + (size_t)(n0 + r0) * 1024 + q0;
  const float* Wb1 = W + (size_t)(n0 + r1) * 1024 + q0;

  f32x4 acc[4][4] = {};
  float4 vb[4];

#define LDB(k)                                                              \
  { vb[0] = *(const float4*)(Wb0 + (k));  vb[1] = *(const float4*)(Wb0 + (k) + 4); \
    vb[2] = *(const float4*)(Wb1 + (k));  vb[3] = *(const float4*)(Wb1 + (k) + 4); }
#define STB(buf)                                                            \
  { *(bf16x8*)&Bs[buf][tid * 8]         = cvt8(vb[0], vb[1]);               \
    *(bf16x8*)&Bs[buf][(tid + 256) * 8] = cvt8(vb[2], vb[3]); }

  // prologue
  glds16(X + (size_t)(m0 + ar0) * 1024 + ac0, &As[0][cb0]);
  glds16(X + (size_t)(m0 + ar1) * 1024 + ac1, &As[0][cb1]);
  LDB(0);
  STB(0);

  int pb = 0;
  for (int k0 = 0; k0 < 1024; k0 += 32, pb ^= 1) {
    __syncthreads();
    const bool pre = k0 + 32 < 1024;
    if (pre) {
      const int kn = k0 + 32;
      glds16(X + (size_t)(m0 + ar0) * 1024 + kn + ac0, &As[pb ^ 1][cb0]);
      glds16(X + (size_t)(m0 + ar1) * 1024 + kn + ac1, &As[pb ^ 1][cb1]);
      LDB(kn);
    }

    bf16x8 a[4], b[4];
#pragma unroll
    for (int j = 0; j < 4; ++j)
      a[j] = *(const bf16x8*)&As[pb][(wm + j * 16 + (lane & 15)) * 32 + (lane >> 4) * 8];
#pragma unroll
    for (int j = 0; j < 4; ++j)
      b[j] = *(const bf16x8*)&Bs[pb][(wn + j * 16 + (lane & 15)) * 32 + (lane >> 4) * 8];
#pragma unroll
    for (int mi = 0; mi < 4; ++mi)
#pragma unroll
      for (int ni = 0; ni < 4; ++ni)
        acc[mi][ni] = __builtin_amdgcn_mfma_f32_16x16x32_bf16(a[mi], b[ni], acc[mi][ni], 0, 0, 0);

    if (pre) STB(pb ^ 1);
  }

#pragma unroll
  for (int mi = 0; mi < 4; ++mi) {
    const int row = m0 + wm + mi * 16 + (lane >> 4) * 4;
#pragma unroll
    for (int ni = 0; ni < 4; ++ni) {
      const int col = n0 + wn + ni * 16 + (lane & 15);
      const float bvv = bias[col];
#pragma unroll
      for (int r = 0; r < 4; ++r)
        Y[(size_t)(row + r) * 1024 + col] = acc[mi][ni][r] + bvv;
    }
  }
#undef LDB
#undef STB
}

// ---------------------------------------------------------------------------
// Flash attention, causal (R3/R7 version verbatim — measured 57.6 us).
// Paired q-tiles (p, 31-p) share one merged k-loop; double-buffered K/V, one
// barrier per iter; P in registers (16x16x16 PV); defer-max with algebraic
// post-PV fixup; Q pre-scaled by the QKV GEMM.
// ---------------------------------------------------------------------------
__device__ __forceinline__ void attn_tile_step(
    const bf16* Ksb, const bf16* Vtb, const bf16x8 bq[2], int qrow, int k0,
    bool maskit, float& mr, float& lr, f32x4 oacc[4], int l15, int quad)
{
  // ---- S^T = K Q^T ----
  f32x4 sacc[8] = {};
  __builtin_amdgcn_s_setprio(1);
#pragma unroll
  for (int ks = 0; ks < 2; ++ks) {
#pragma unroll
    for (int mb = 0; mb < 8; ++mb) {
      const int row = mb * 16 + l15;
      const int ch  = (ks * 4 + quad) ^ (l15 & 7);   // XOR de-swizzle
      bf16x8 ak = *(const bf16x8*)&Ksb[row * 64 + ch * 8];
      sacc[mb] = __builtin_amdgcn_mfma_f32_16x16x32_bf16(ak, bq[ks], sacc[mb], 0, 0, 0);
    }
  }
  __builtin_amdgcn_s_setprio(0);

  // causal mask (only on the final k-tile of this q-tile)
  if (maskit) {
#pragma unroll
    for (int mb = 0; mb < 8; ++mb) {
      const int kb = k0 + mb * 16 + quad * 4;
#pragma unroll
      for (int r = 0; r < 4; ++r)
        if (kb + r > qrow) sacc[mb][r] = -1e30f;
    }
  }

  // max tree + shuffles — runs in PARALLEL with the exp2/PV chain below
  float mx = -1e30f;
#pragma unroll
  for (int mb = 0; mb < 8; ++mb)
    mx = fmaxf(mx, fmaxf(fmaxf(sacc[mb][0], sacc[mb][1]),
                         fmaxf(sacc[mb][2], sacc[mb][3])));
  mx = fmaxf(mx, __shfl_xor(mx, 16, 64));
  mx = fmaxf(mx, __shfl_xor(mx, 32, 64));

  // speculative exp2 with CURRENT mr (no dependence on mx)
  float sum = 0.0f;
  bf16x4 pwv[8];
#pragma unroll
  for (int mb = 0; mb < 8; ++mb) {
    bf16x4 pw;
#pragma unroll
    for (int r = 0; r < 4; ++r) {
      const float p = __builtin_amdgcn_exp2f(sacc[mb][r] - mr);
      sum += p;
      pw[r] = (bf16)p;
    }
    pwv[mb] = pw;
  }
  sum += __shfl_xor(sum, 16, 64);
  sum += __shfl_xor(sum, 32, 64);

  // ---- O^T += V^T P^T : 16x16x16, P direct from registers ----
  __builtin_amdgcn_s_setprio(1);
#pragma unroll
  for (int mb = 0; mb < 8; ++mb) {
#pragma unroll
    for (int db = 0; db < 4; ++db) {
      const int vch = ((mb * 4 + quad) ^ (l15 & 7)) * 4;
      bf16x4 av = *(const bf16x4*)&Vtb[(db * 16 + l15) * 128 + vch];
      oacc[db] = pv_mfma(av, pwv[mb], oacc[db]);
    }
  }
  __builtin_amdgcn_s_setprio(0);

  lr += sum;
  // rare fixup: rescale AFTER accumulation (exact: O' = a*(O_old + P·V))
  if (!__all(mx <= mr + 8.0f)) {
    const float mnew  = fmaxf(mr, mx);
    const float alpha = __builtin_amdgcn_exp2f(mr - mnew);
    lr *= alpha;
#pragma unroll
    for (int db = 0; db < 4; ++db)
#pragma unroll
      for (int r = 0; r < 4; ++r) oacc[db][r] *= alpha;
    mr = mnew;
  }
}

__global__ __launch_bounds__(256, 2) void attn_causal(
    const bf16* __restrict__ Q, const bf16* __restrict__ K,
    const bf16* __restrict__ V, bf16* __restrict__ O)
{
  // XCD-chunked decode: all 16 pair-blocks of a bh land on one XCD (lin%8).
  const int lin  = blockIdx.x;               // 0..511
  const int slot = lin >> 3;                 // 0..63
  const int bh   = (lin & 7) * 4 + (slot >> 4);
  const int pair = slot & 15;
  const int b    = bh >> 4;
  const int h    = bh & 15;

  const int tid  = threadIdx.x;
  const int lane = tid & 63;
  const int wave = tid >> 6;
  const int quad = lane >> 4;
  const int l15  = lane & 15;
  const size_t headoff = (size_t)b * S_ * H_ + (size_t)h * HD_;
  const bf16* Kp = K + headoff;
  const bf16* Vp = V + headoff;

  __shared__ __align__(16) bf16 Ks[2][128 * 64];    // unpadded, XOR-swizzled
  __shared__ __align__(16) bf16 Vt[2][64 * 128];    // Vt[d][key], XOR-swizzled

  const int qlo = pair, qhi = 31 - pair;
  const int nl  = (qlo >> 1) + 1;      // 1..8
  const int nh  = (qhi >> 1) + 1;      // 9..16  (nl < nh always)
  const int qrowL = qlo * 64 + wave * 16 + l15;
  const int qrowH = qhi * 64 + wave * 16 + l15;

  // Q fragments in registers for the whole block (pre-scaled by QKV GEMM)
  bf16x8 bqL[2], bqH[2];
  bqL[0] = *(const bf16x8*)(Q + headoff + (size_t)qrowL * H_ + quad * 8);
  bqL[1] = *(const bf16x8*)(Q + headoff + (size_t)qrowL * H_ + 32 + quad * 8);
  bqH[0] = *(const bf16x8*)(Q + headoff + (size_t)qrowH * H_ + quad * 8);
  bqH[1] = *(const bf16x8*)(Q + headoff + (size_t)qrowH * H_ + 32 + quad * 8);

  const int vr = lane * 2;          // V: two adjacent key rows per thread
  const int vc = wave * 16;         //    16 of 64 head dims per wave

#define STAGE_K(k0_, buf_)                                                  \
  {                                                                         \
    _Pragma("unroll")                                                       \
    for (int j = 0; j < 4; ++j) {                                           \
      const int n = j * 256 + tid;                                          \
      const int row = n >> 3;                                               \
      const int cg  = (n & 7) ^ (row & 7);                                  \
      glds16(Kp + (size_t)((k0_) + row) * H_ + cg * 8,                      \
             &Ks[buf_][(j * 256 + wave * 64) * 8]);                         \
    }                                                                       \
  }

#define LOAD_V(k0_)                                                         \
  {                                                                         \
    vreg[0] = *(const bf16x8*)(Vp + (size_t)((k0_) + vr) * H_ + vc);        \
    vreg[1] = *(const bf16x8*)(Vp + (size_t)((k0_) + vr) * H_ + vc + 8);    \
    vreg[2] = *(const bf16x8*)(Vp + (size_t)((k0_) + vr + 1) * H_ + vc);    \
    vreg[3] = *(const bf16x8*)(Vp + (size_t)((k0_) + vr + 1) * H_ + vc + 8);\
  }

// Vt write with chunk-XOR swizzle: chunk (4 elems) index = (vr>>2) ^ (row&7).
#define WRITE_V(buf_)                                                       \
  {                                                                         \
    _Pragma("unroll")                                                       \
    for (int e = 0; e < 8; ++e) {                                           \
      const int sw = (((vr >> 2) ^ e) * 4) + (vr & 3);                      \
      bf16x2 p0; p0[0] = vreg[0][e]; p0[1] = vreg[2][e];                    \
      *(bf16x2*)&Vt[buf_][(vc + e) * 128 + sw] = p0;                        \
      bf16x2 p1; p1[0] = vreg[1][e]; p1[1] = vreg[3][e];                    \
      *(bf16x2*)&Vt[buf_][(vc + 8 + e) * 128 + sw] = p1;                    \
    }                                                                       \
  }

  bf16x8 vreg[4];

  // prologue: tile 0 -> buf 0
  STAGE_K(0, 0);
  LOAD_V(0);
  WRITE_V(0);
  __syncthreads();

  float mrL = 0.0f, lrL = 0.0f, mrH = 0.0f, lrH = 0.0f;
  f32x4 oL[4] = {}, oH[4] = {};

  for (int it = 0; it < nh; ++it) {
    const int c = it & 1;
    const bool pre = (it + 1 < nh);

    if (pre) {                       // prefetch tile it+1 into buf c^1
      STAGE_K((it + 1) * 128, c ^ 1);
      LOAD_V((it + 1) * 128);
    }

    attn_tile_step(Ks[c], Vt[c], bqH, qrowH, it * 128, it == nh - 1,
                   mrH, lrH, oH, l15, quad);
    if (it < nl)
      attn_tile_step(Ks[c], Vt[c], bqL, qrowL, it * 128, it == nl - 1,
                     mrL, lrL, oL, l15, quad);

    if (pre) {
      WRITE_V(c ^ 1);                // reg->LDS after compute (write-late)
      __syncthreads();               // drains glds + V writes; publishes c^1
    }
  }

  // epilogues
  const float invL = 1.0f / lrL;
#pragma unroll
  for (int db = 0; db < 4; ++db) {
    bf16x4 o;
#pragma unroll
    for (int r = 0; r < 4; ++r) o[r] = (bf16)(oL[db][r] * invL);
    *(bf16x4*)(O + headoff + (size_t)qrowL * H_ + db * 16 + quad * 4) = o;
  }
  const float invH = 1.0f / lrH;
#pragma unroll
  for (int db = 0; db < 4; ++db) {
    bf16x4 o;
#pragma unroll
    for (int r = 0; r < 4; ++r) o[r] = (bf16)(oH[db][r] * invH);
    *(bf16x4*)(O + headoff + (size_t)qrowH * H_ + db * 16 + quad * 4) = o;
  }
#undef STAGE_K
#undef LOAD_V
#undef WRITE_V
}

extern "C" void kernel_launch(void* const* d_in, const int* in_sizes, int n_in,
                              void* d_out, int out_size, void* d_ws, size_t ws_size,
                              hipStream_t stream) {
  const float* hs = (const float*)d_in[0];
  const float* Wq = (const float*)d_in[1]; const float* bq = (const float*)d_in[2];
  const float* Wk = (const float*)d_in[3]; const float* bk = (const float*)d_in[4];
  const float* Wv = (const float*)d_in[5]; const float* bv = (const float*)d_in[6];
  const float* Wo = (const float*)d_in[7]; const float* bo = (const float*)d_in[8];
  float* out = (float*)d_out;

  const size_t elems = (size_t)B_ * S_ * H_;   // 4,194,304
  // workspace (40 MB): Qw | Kw | Vw | AO, 8 MB each (bf16)
  bf16* Qw = (bf16*)d_ws;
  bf16* Kw = Qw + elems;
  bf16* Vw = Kw + elems;
  bf16* AO = Vw + elems;

  const float QSCL = 0.125f * 1.44269504f;   // (1/sqrt(64)) * log2(e)

  // 3 dispatches: conversion folded into the GEMM staging paths.
  gemm_qkv_f32<<<dim3(768), dim3(256), 0, stream>>>(
      hs, Wq, Wk, Wv, bq, bk, bv, Qw, Kw, Vw, QSCL);

  attn_causal<<<dim3(512), dim3(256), 0, stream>>>(Qw, Kw, Vw, AO);

  gemm_o_f32w<<<dim3(256), dim3(256), 0, stream>>>(AO, Wo, bo, out);
}

// Round 10
// 199.033 us; speedup vs baseline: 1.2433x; 1.1020x over previous
//
#include <hip/hip_runtime.h>
#include <stdint.h>

typedef __bf16 bf16;
typedef __attribute__((ext_vector_type(2))) __bf16 bf16x2;
typedef __attribute__((ext_vector_type(4))) __bf16 bf16x4;
typedef __attribute__((ext_vector_type(8))) __bf16 bf16x8;
typedef __attribute__((ext_vector_type(4))) float f32x4;
typedef __attribute__((ext_vector_type(4))) short s16x4;

#define B_  2
#define S_  2048
#define H_  1024
#define NH_ 16
#define HD_ 64

// async 16B global->LDS. LDS dest = wave-uniform base + lane*16.
__device__ __forceinline__ void glds16(const bf16* g, bf16* l) {
  __builtin_amdgcn_global_load_lds(
      (const __attribute__((address_space(1))) uint32_t*)g,
      (__attribute__((address_space(3))) uint32_t*)l, 16, 0, 0);
}

// PV MFMA: 16x16x16 bf16 — B operand layout (k=quad*4+e, col=l15) matches the
// S^T MFMA D layout exactly, so softmax P registers feed it with NO relayout.
__device__ __forceinline__ f32x4 pv_mfma(bf16x4 a, bf16x4 b, f32x4 c) {
#if __has_builtin(__builtin_amdgcn_mfma_f32_16x16x16bf16_1k)
  union U { bf16x4 h; s16x4 s; };
  U ua; ua.h = a;
  U ub; ub.h = b;
  return __builtin_amdgcn_mfma_f32_16x16x16bf16_1k(ua.s, ub.s, c, 0, 0, 0);
#else
  f32x4 d;
  asm volatile("v_mfma_f32_16x16x16_bf16 %0, %1, %2, %3\n\ts_nop 7\n\ts_nop 7"
               : "=v"(d) : "v"(a), "v"(b), "v"(c));
  return d;
#endif
}

// ---------------------------------------------------------------------------
// fp32 -> bf16 conversion: y=0 hidden_states, y=1..4 weight matrices.
// (Proven: the bf16+glds16 GEMM path beats f32-direct reg-staging by far
//  more than this kernel costs — R8/R9 falsified the f32-direct variant.)
// ---------------------------------------------------------------------------
__global__ __launch_bounds__(256) void cvt_f32_bf16(
    const float* __restrict__ s0, bf16* __restrict__ d0, int n0,
    const float* __restrict__ s1, bf16* __restrict__ d1,
    const float* __restrict__ s2, bf16* __restrict__ d2,
    const float* __restrict__ s3, bf16* __restrict__ d3,
    const float* __restrict__ s4, bf16* __restrict__ d4, int nw)
{
  const float* s; bf16* d; int n;
  switch (blockIdx.y) {
    case 0:  s = s0; d = d0; n = n0; break;
    case 1:  s = s1; d = d1; n = nw; break;
    case 2:  s = s2; d = d2; n = nw; break;
    case 3:  s = s3; d = d3; n = nw; break;
    default: s = s4; d = d4; n = nw; break;
  }
  const int i = (blockIdx.x * 256 + threadIdx.x) * 8;
  if (i >= n) return;
  float4 v0 = *(const float4*)(s + i);
  float4 v1 = *(const float4*)(s + i + 4);
  bf16x8 o;
  o[0] = (bf16)v0.x; o[1] = (bf16)v0.y; o[2] = (bf16)v0.z; o[3] = (bf16)v0.w;
  o[4] = (bf16)v1.x; o[5] = (bf16)v1.y; o[6] = (bf16)v1.z; o[7] = (bf16)v1.w;
  *(bf16x8*)(d + i) = o;
}

// ---------------------------------------------------------------------------
// QKV GEMM (R2-proven): Y = (X·W^T + bias) * ysc, all-bf16 via glds16.
// 128x128 tile, BK=32, double-buffered LDS, one barrier per K-iter.
// z-slice picks Wq/Wk/Wv.  Grid 8 x 32 x 3 = 768 blocks (3/CU).
// ---------------------------------------------------------------------------
__global__ __launch_bounds__(256) void gemm_qkv(
    const bf16* __restrict__ X,
    const bf16* __restrict__ W0, const bf16* __restrict__ W1, const bf16* __restrict__ W2,
    const float* __restrict__ b0, const float* __restrict__ b1, const float* __restrict__ b2,
    bf16* __restrict__ Y0, bf16* __restrict__ Y1, bf16* __restrict__ Y2,
    float ys0, int M, int N, int K)
{
  const bf16* W; const float* bias; bf16* Y; float ysc;
  if (blockIdx.z == 0)      { W = W0; bias = b0; Y = Y0; ysc = ys0; }
  else if (blockIdx.z == 1) { W = W1; bias = b1; Y = Y1; ysc = 1.0f; }
  else                      { W = W2; bias = b2; Y = Y2; ysc = 1.0f; }

  __shared__ __align__(16) bf16 As[2][128 * 32];
  __shared__ __align__(16) bf16 Bs[2][128 * 32];

  const int tid  = threadIdx.x;
  const int lane = tid & 63;
  const int wave = tid >> 6;
  const int m0 = blockIdx.y * 128;
  const int n0 = blockIdx.x * 128;
  const int wm = (wave >> 1) * 64;
  const int wn = (wave & 1) * 64;

  const int r0 = tid >> 2,            c0 = (tid & 3) * 8;
  const int r1 = (256 + tid) >> 2,    c1 = ((256 + tid) & 3) * 8;
  const int cb0 = (wave * 64) * 8;
  const int cb1 = (256 + wave * 64) * 8;

  f32x4 acc[4][4] = {};

  glds16(X + (size_t)(m0 + r0) * K + c0, &As[0][cb0]);
  glds16(W + (size_t)(n0 + r0) * K + c0, &Bs[0][cb0]);
  glds16(X + (size_t)(m0 + r1) * K + c1, &As[0][cb1]);
  glds16(W + (size_t)(n0 + r1) * K + c1, &Bs[0][cb1]);

  int pb = 0;
  for (int k0 = 0; k0 < K; k0 += 32, pb ^= 1) {
    __syncthreads();

    if (k0 + 32 < K) {
      const int kn = k0 + 32;
      glds16(X + (size_t)(m0 + r0) * K + kn + c0, &As[pb ^ 1][cb0]);
      glds16(W + (size_t)(n0 + r0) * K + kn + c0, &Bs[pb ^ 1][cb0]);
      glds16(X + (size_t)(m0 + r1) * K + kn + c1, &As[pb ^ 1][cb1]);
      glds16(W + (size_t)(n0 + r1) * K + kn + c1, &Bs[pb ^ 1][cb1]);
    }

    bf16x8 a[4], b[4];
#pragma unroll
    for (int i = 0; i < 4; ++i)
      a[i] = *(const bf16x8*)&As[pb][(wm + i * 16 + (lane & 15)) * 32 + (lane >> 4) * 8];
#pragma unroll
    for (int i = 0; i < 4; ++i)
      b[i] = *(const bf16x8*)&Bs[pb][(wn + i * 16 + (lane & 15)) * 32 + (lane >> 4) * 8];
#pragma unroll
    for (int mi = 0; mi < 4; ++mi)
#pragma unroll
      for (int ni = 0; ni < 4; ++ni)
        acc[mi][ni] = __builtin_amdgcn_mfma_f32_16x16x32_bf16(a[mi], b[ni], acc[mi][ni], 0, 0, 0);
  }

#pragma unroll
  for (int mi = 0; mi < 4; ++mi) {
    const int row = m0 + wm + mi * 16 + (lane >> 4) * 4;
#pragma unroll
    for (int ni = 0; ni < 4; ++ni) {
      const int col = n0 + wn + ni * 16 + (lane & 15);
      const float bv = bias[col];
#pragma unroll
      for (int r = 0; r < 4; ++r)
        Y[(size_t)(row + r) * N + col] = (bf16)((acc[mi][ni][r] + bv) * ysc);
    }
  }
}

// ---------------------------------------------------------------------------
// O-projection, R10: 64x128 tile -> grid 8 x 64 = 512 blocks = 2 blocks/CU
// (was 128x128 @ 256 blocks = 1/CU, grid-limited occupancy on a latency-
// exposed 2-barrier structure).  Wave tile 32x64, acc[2][4], 8 MFMA/iter.
// LDS 24 KB.  Same glds16 staging discipline.
// ---------------------------------------------------------------------------
__global__ __launch_bounds__(256) void gemm_o_64(
    const bf16* __restrict__ X, const bf16* __restrict__ W,
    const float* __restrict__ bias, float* __restrict__ Y)
{
  constexpr int K = 1024, N = 1024;
  __shared__ __align__(16) bf16 As[2][64 * 32];
  __shared__ __align__(16) bf16 Bs[2][128 * 32];

  const int tid  = threadIdx.x;
  const int lane = tid & 63;
  const int wave = tid >> 6;
  const int m0 = blockIdx.y * 64;
  const int n0 = blockIdx.x * 128;
  const int wm = (wave >> 1) * 32;
  const int wn = (wave & 1) * 64;

  // A: 256 chunks (1/thread): row=tid>>2, col8=(tid&3)*8
  const int ar = tid >> 2,  ac = (tid & 3) * 8;
  // B: 512 chunks (2/thread): same map as the proven 128-row staging
  const int br0 = tid >> 2,          bc0 = (tid & 3) * 8;
  const int br1 = (256 + tid) >> 2,  bc1 = ((256 + tid) & 3) * 8;
  const int acb  = (wave * 64) * 8;
  const int bcb0 = (wave * 64) * 8;
  const int bcb1 = (256 + wave * 64) * 8;

  f32x4 acc[2][4] = {};

  glds16(X + (size_t)(m0 + ar) * K + ac,   &As[0][acb]);
  glds16(W + (size_t)(n0 + br0) * K + bc0, &Bs[0][bcb0]);
  glds16(W + (size_t)(n0 + br1) * K + bc1, &Bs[0][bcb1]);

  int pb = 0;
  for (int k0 = 0; k0 < K; k0 += 32, pb ^= 1) {
    __syncthreads();

    if (k0 + 32 < K) {
      const int kn = k0 + 32;
      glds16(X + (size_t)(m0 + ar) * K + kn + ac,   &As[pb ^ 1][acb]);
      glds16(W + (size_t)(n0 + br0) * K + kn + bc0, &Bs[pb ^ 1][bcb0]);
      glds16(W + (size_t)(n0 + br1) * K + kn + bc1, &Bs[pb ^ 1][bcb1]);
    }

    bf16x8 a[2], b[4];
#pragma unroll
    for (int i = 0; i < 2; ++i)
      a[i] = *(const bf16x8*)&As[pb][(wm + i * 16 + (lane & 15)) * 32 + (lane >> 4) * 8];
#pragma unroll
    for (int i = 0; i < 4; ++i)
      b[i] = *(const bf16x8*)&Bs[pb][(wn + i * 16 + (lane & 15)) * 32 + (lane >> 4) * 8];
#pragma unroll
    for (int mi = 0; mi < 2; ++mi)
#pragma unroll
      for (int ni = 0; ni < 4; ++ni)
        acc[mi][ni] = __builtin_amdgcn_mfma_f32_16x16x32_bf16(a[mi], b[ni], acc[mi][ni], 0, 0, 0);
  }

#pragma unroll
  for (int mi = 0; mi < 2; ++mi) {
    const int row = m0 + wm + mi * 16 + (lane >> 4) * 4;
#pragma unroll
    for (int ni = 0; ni < 4; ++ni) {
      const int col = n0 + wn + ni * 16 + (lane & 15);
      const float bv = bias[col];
#pragma unroll
      for (int r = 0; r < 4; ++r)
        Y[(size_t)(row + r) * N + col] = acc[mi][ni][r] + bv;
    }
  }
}

// ---------------------------------------------------------------------------
// Flash attention, causal (R3/R7 version verbatim — measured 57.5 us).
// Paired q-tiles (p, 31-p) share one merged k-loop; double-buffered K/V, one
// barrier per iter; P in registers (16x16x16 PV); defer-max with algebraic
// post-PV fixup; Q pre-scaled by the QKV GEMM.
// ---------------------------------------------------------------------------
__device__ __forceinline__ void attn_tile_step(
    const bf16* Ksb, const bf16* Vtb, const bf16x8 bq[2], int qrow, int k0,
    bool maskit, float& mr, float& lr, f32x4 oacc[4], int l15, int quad)
{
  // ---- S^T = K Q^T ----
  f32x4 sacc[8] = {};
  __builtin_amdgcn_s_setprio(1);
#pragma unroll
  for (int ks = 0; ks < 2; ++ks) {
#pragma unroll
    for (int mb = 0; mb < 8; ++mb) {
      const int row = mb * 16 + l15;
      const int ch  = (ks * 4 + quad) ^ (l15 & 7);   // XOR de-swizzle
      bf16x8 ak = *(const bf16x8*)&Ksb[row * 64 + ch * 8];
      sacc[mb] = __builtin_amdgcn_mfma_f32_16x16x32_bf16(ak, bq[ks], sacc[mb], 0, 0, 0);
    }
  }
  __builtin_amdgcn_s_setprio(0);

  // causal mask (only on the final k-tile of this q-tile)
  if (maskit) {
#pragma unroll
    for (int mb = 0; mb < 8; ++mb) {
      const int kb = k0 + mb * 16 + quad * 4;
#pragma unroll
      for (int r = 0; r < 4; ++r)
        if (kb + r > qrow) sacc[mb][r] = -1e30f;
    }
  }

  // max tree + shuffles — runs in PARALLEL with the exp2/PV chain below
  float mx = -1e30f;
#pragma unroll
  for (int mb = 0; mb < 8; ++mb)
    mx = fmaxf(mx, fmaxf(fmaxf(sacc[mb][0], sacc[mb][1]),
                         fmaxf(sacc[mb][2], sacc[mb][3])));
  mx = fmaxf(mx, __shfl_xor(mx, 16, 64));
  mx = fmaxf(mx, __shfl_xor(mx, 32, 64));

  // speculative exp2 with CURRENT mr (no dependence on mx)
  float sum = 0.0f;
  bf16x4 pwv[8];
#pragma unroll
  for (int mb = 0; mb < 8; ++mb) {
    bf16x4 pw;
#pragma unroll
    for (int r = 0; r < 4; ++r) {
      const float p = __builtin_amdgcn_exp2f(sacc[mb][r] - mr);
      sum += p;
      pw[r] = (bf16)p;
    }
    pwv[mb] = pw;
  }
  sum += __shfl_xor(sum, 16, 64);
  sum += __shfl_xor(sum, 32, 64);

  // ---- O^T += V^T P^T : 16x16x16, P direct from registers ----
  __builtin_amdgcn_s_setprio(1);
#pragma unroll
  for (int mb = 0; mb < 8; ++mb) {
#pragma unroll
    for (int db = 0; db < 4; ++db) {
      const int vch = ((mb * 4 + quad) ^ (l15 & 7)) * 4;
      bf16x4 av = *(const bf16x4*)&Vtb[(db * 16 + l15) * 128 + vch];
      oacc[db] = pv_mfma(av, pwv[mb], oacc[db]);
    }
  }
  __builtin_amdgcn_s_setprio(0);

  lr += sum;
  // rare fixup: rescale AFTER accumulation (exact: O' = a*(O_old + P·V))
  if (!__all(mx <= mr + 8.0f)) {
    const float mnew  = fmaxf(mr, mx);
    const float alpha = __builtin_amdgcn_exp2f(mr - mnew);
    lr *= alpha;
#pragma unroll
    for (int db = 0; db < 4; ++db)
#pragma unroll
      for (int r = 0; r < 4; ++r) oacc[db][r] *= alpha;
    mr = mnew;
  }
}

__global__ __launch_bounds__(256, 2) void attn_causal(
    const bf16* __restrict__ Q, const bf16* __restrict__ K,
    const bf16* __restrict__ V, bf16* __restrict__ O)
{
  // XCD-chunked decode: all 16 pair-blocks of a bh land on one XCD (lin%8).
  const int lin  = blockIdx.x;               // 0..511
  const int slot = lin >> 3;                 // 0..63
  const int bh   = (lin & 7) * 4 + (slot >> 4);
  const int pair = slot & 15;
  const int b    = bh >> 4;
  const int h    = bh & 15;

  const int tid  = threadIdx.x;
  const int lane = tid & 63;
  const int wave = tid >> 6;
  const int quad = lane >> 4;
  const int l15  = lane & 15;
  const size_t headoff = (size_t)b * S_ * H_ + (size_t)h * HD_;
  const bf16* Kp = K + headoff;
  const bf16* Vp = V + headoff;

  __shared__ __align__(16) bf16 Ks[2][128 * 64];    // unpadded, XOR-swizzled
  __shared__ __align__(16) bf16 Vt[2][64 * 128];    // Vt[d][key], XOR-swizzled

  const int qlo = pair, qhi = 31 - pair;
  const int nl  = (qlo >> 1) + 1;      // 1..8
  const int nh  = (qhi >> 1) + 1;      // 9..16  (nl < nh always)
  const int qrowL = qlo * 64 + wave * 16 + l15;
  const int qrowH = qhi * 64 + wave * 16 + l15;

  // Q fragments in registers for the whole block (pre-scaled by QKV GEMM)
  bf16x8 bqL[2], bqH[2];
  bqL[0] = *(const bf16x8*)(Q + headoff + (size_t)qrowL * H_ + quad * 8);
  bqL[1] = *(const bf16x8*)(Q + headoff + (size_t)qrowL * H_ + 32 + quad * 8);
  bqH[0] = *(const bf16x8*)(Q + headoff + (size_t)qrowH * H_ + quad * 8);
  bqH[1] = *(const bf16x8*)(Q + headoff + (size_t)qrowH * H_ + 32 + quad * 8);

  const int vr = lane * 2;          // V: two adjacent key rows per thread
  const int vc = wave * 16;         //    16 of 64 head dims per wave

#define STAGE_K(k0_, buf_)                                                  \
  {                                                                         \
    _Pragma("unroll")                                                       \
    for (int j = 0; j < 4; ++j) {                                           \
      const int n = j * 256 + tid;                                          \
      const int row = n >> 3;                                               \
      const int cg  = (n & 7) ^ (row & 7);                                  \
      glds16(Kp + (size_t)((k0_) + row) * H_ + cg * 8,                      \
             &Ks[buf_][(j * 256 + wave * 64) * 8]);                         \
    }                                                                       \
  }

#define LOAD_V(k0_)                                                         \
  {                                                                         \
    vreg[0] = *(const bf16x8*)(Vp + (size_t)((k0_) + vr) * H_ + vc);        \
    vreg[1] = *(const bf16x8*)(Vp + (size_t)((k0_) + vr) * H_ + vc + 8);    \
    vreg[2] = *(const bf16x8*)(Vp + (size_t)((k0_) + vr + 1) * H_ + vc);    \
    vreg[3] = *(const bf16x8*)(Vp + (size_t)((k0_) + vr + 1) * H_ + vc + 8);\
  }

// Vt write with chunk-XOR swizzle: chunk (4 elems) index = (vr>>2) ^ (row&7).
#define WRITE_V(buf_)                                                       \
  {                                                                         \
    _Pragma("unroll")                                                       \
    for (int e = 0; e < 8; ++e) {                                           \
      const int sw = (((vr >> 2) ^ e) * 4) + (vr & 3);                      \
      bf16x2 p0; p0[0] = vreg[0][e]; p0[1] = vreg[2][e];                    \
      *(bf16x2*)&Vt[buf_][(vc + e) * 128 + sw] = p0;                        \
      bf16x2 p1; p1[0] = vreg[1][e]; p1[1] = vreg[3][e];                    \
      *(bf16x2*)&Vt[buf_][(vc + 8 + e) * 128 + sw] = p1;                    \
    }                                                                       \
  }

  bf16x8 vreg[4];

  // prologue: tile 0 -> buf 0
  STAGE_K(0, 0);
  LOAD_V(0);
  WRITE_V(0);
  __syncthreads();

  float mrL = 0.0f, lrL = 0.0f, mrH = 0.0f, lrH = 0.0f;
  f32x4 oL[4] = {}, oH[4] = {};

  for (int it = 0; it < nh; ++it) {
    const int c = it & 1;
    const bool pre = (it + 1 < nh);

    if (pre) {                       // prefetch tile it+1 into buf c^1
      STAGE_K((it + 1) * 128, c ^ 1);
      LOAD_V((it + 1) * 128);
    }

    attn_tile_step(Ks[c], Vt[c], bqH, qrowH, it * 128, it == nh - 1,
                   mrH, lrH, oH, l15, quad);
    if (it < nl)
      attn_tile_step(Ks[c], Vt[c], bqL, qrowL, it * 128, it == nl - 1,
                     mrL, lrL, oL, l15, quad);

    if (pre) {
      WRITE_V(c ^ 1);                // reg->LDS after compute (write-late)
      __syncthreads();               // drains glds + V writes; publishes c^1
    }
  }

  // epilogues
  const float invL = 1.0f / lrL;
#pragma unroll
  for (int db = 0; db < 4; ++db) {
    bf16x4 o;
#pragma unroll
    for (int r = 0; r < 4; ++r) o[r] = (bf16)(oL[db][r] * invL);
    *(bf16x4*)(O + headoff + (size_t)qrowL * H_ + db * 16 + quad * 4) = o;
  }
  const float invH = 1.0f / lrH;
#pragma unroll
  for (int db = 0; db < 4; ++db) {
    bf16x4 o;
#pragma unroll
    for (int r = 0; r < 4; ++r) o[r] = (bf16)(oH[db][r] * invH);
    *(bf16x4*)(O + headoff + (size_t)qrowH * H_ + db * 16 + quad * 4) = o;
  }
#undef STAGE_K
#undef LOAD_V
#undef WRITE_V
}

extern "C" void kernel_launch(void* const* d_in, const int* in_sizes, int n_in,
                              void* d_out, int out_size, void* d_ws, size_t ws_size,
                              hipStream_t stream) {
  const float* hs = (const float*)d_in[0];
  const float* Wq = (const float*)d_in[1]; const float* bq = (const float*)d_in[2];
  const float* Wk = (const float*)d_in[3]; const float* bk = (const float*)d_in[4];
  const float* Wv = (const float*)d_in[5]; const float* bv = (const float*)d_in[6];
  const float* Wo = (const float*)d_in[7]; const float* bo = (const float*)d_in[8];
  float* out = (float*)d_out;

  const size_t elems = (size_t)B_ * S_ * H_;   // 4,194,304
  const size_t wel   = (size_t)H_ * H_;        // 1,048,576
  // workspace (40 MB): [hsb | AO aliased 8MB][W bf16 8MB][Q 8][K 8][V 8]
  bf16* hsb = (bf16*)d_ws;      // read only by QKV GEMM
  bf16* AO  = hsb;              // written by attn (hsb dead by then)
  bf16* Wqb = hsb + elems;
  bf16* Wkb = Wqb + wel;
  bf16* Wvb = Wkb + wel;
  bf16* Wob = Wvb + wel;
  bf16* Qw  = Wob + wel;
  bf16* Kw  = Qw + elems;
  bf16* Vw  = Kw + elems;

  cvt_f32_bf16<<<dim3(2048, 5), dim3(256), 0, stream>>>(
      hs, hsb, (int)elems, Wq, Wqb, Wk, Wkb, Wv, Wvb, Wo, Wob, (int)wel);

  const int M = B_ * S_;   // 4096
  const float QSCL = 0.125f * 1.44269504f;   // (1/sqrt(64)) * log2(e)

  gemm_qkv<<<dim3(H_ / 128, M / 128, 3), dim3(256), 0, stream>>>(
      hsb, Wqb, Wkb, Wvb, bq, bk, bv, Qw, Kw, Vw, QSCL, M, H_, H_);

  attn_causal<<<dim3(512), dim3(256), 0, stream>>>(Qw, Kw, Vw, AO);

  gemm_o_64<<<dim3(8, 64), dim3(256), 0, stream>>>(AO, Wob, bo, out);
}